// Round 2
// baseline (138.301 us; speedup 1.0000x reference)
//
#include <hip/hip_runtime.h>
#include <hip/hip_cooperative_groups.h>

namespace cg = cooperative_groups;

// Problem constants
#define P_ROWS   1024
#define N_IN     784
#define N_OUT    128
#define M_ROWS   785                 // N_IN + 1 (bias row)

// RATIO = G_MIN/(G_MAX-G_MIN);  L_AVG = log2(n_avg), n_avg = 2.132
#define RATIO_F  ((float)((1.0/983.3) / ((1.0/281.3) - (1.0/983.3))))
#define L_AVG_F  1.0922076f
#define LN2_F    0.6931472f

// GEMM shape: K = m-rows * 4 Taylor terms. 11 chunks of 72 m-rows (288 K).
// (chunk 10 covers m=720..791; m>=785 handled only in its step s=8 tail)
#define NCHK   11
#define MCH    72
#define NSTEP  9                     // 288 K / 32
#define NB_MAIN (64 * NCHK)          // 64 p-blocks x 11 chunks = 704 (<= 3/CU)

typedef _Float16 half8 __attribute__((ext_vector_type(8)));
typedef float    f32x4 __attribute__((ext_vector_type(4)));

// ---------------------------------------------------------------------------
// On-the-fly Taylor coefficients C_0..C_3 for weight row m, column n.
//   C_0 = 0.5(wp-wn); C_j = (Ap*Dp^j - An*Dn^j)/j!, A = c0 + 0.5w,
//   D = ln(n_param/n_avg).
__device__ __forceinline__ void genB(int m, int n, float c0,
        const float* __restrict__ wp, const float* __restrict__ wn,
        const float* __restrict__ npar, float C[4]) {
    float wpv = wp[(size_t)m * N_OUT + n];
    float wnv = wn[(size_t)m * N_OUT + n];
    float2 nv = *(const float2*)(npar + (size_t)m * (2 * N_OUT) + 2 * n);
    float Dp = LN2_F * (__builtin_amdgcn_logf(nv.x) - L_AVG_F);
    float Dn = LN2_F * (__builtin_amdgcn_logf(nv.y) - L_AVG_F);
    float Ap = c0 + 0.5f * wpv;
    float An = c0 + 0.5f * wnv;
    float ApD = Ap * Dp,    AnD = An * Dn;
    float ApD2 = ApD * Dp,  AnD2 = AnD * Dn;
    float ApD3 = ApD2 * Dp, AnD3 = AnD2 * Dn;
    C[0] = Ap - An;                              // c0 cancels
    C[1] = ApD - AnD;
    C[2] = (ApD2 - AnD2) * 0.5f;
    C[3] = (ApD3 - AnD3) * (1.0f / 6.0f);
}

// Bias row (m == N_IN): weights come from bp/bn.
__device__ __forceinline__ void genBias(int n, float c0,
        const float* __restrict__ bp, const float* __restrict__ bn,
        const float* __restrict__ npar, float C[4]) {
    float wpv = bp[n];
    float wnv = bn[n];
    float2 nv = *(const float2*)(npar + (size_t)N_IN * (2 * N_OUT) + 2 * n);
    float Dp = LN2_F * (__builtin_amdgcn_logf(nv.x) - L_AVG_F);
    float Dn = LN2_F * (__builtin_amdgcn_logf(nv.y) - L_AVG_F);
    float Ap = c0 + 0.5f * wpv;
    float An = c0 + 0.5f * wnv;
    float ApD = Ap * Dp,    AnD = An * Dn;
    float ApD2 = ApD * Dp,  AnD2 = AnD * Dn;
    float ApD3 = ApD2 * Dp, AnD3 = AnD2 * Dn;
    C[0] = Ap - An;
    C[1] = ApD - AnD;
    C[2] = (ApD2 - AnD2) * 0.5f;
    C[3] = (ApD3 - AnD3) * (1.0f / 6.0f);
}

// ---------------------------------------------------------------------------
// Single fused cooperative kernel.
// Phase A (before grid.sync): zero out[], per-block max|w| partial, and
//   stage F (A-operand, mw-independent) into LDS — x-load latency hides
//   under the grid-sync wait.
// Phase B (after grid.sync): reduce 704 partials -> mw -> c0, then the
//   MFMA micro-GEMM with on-the-fly B generation; atomic accumulate into
//   out (11 adds/output, zeroed in phase A).
__global__ __launch_bounds__(256, 3) void memristor_fused(
        const float* __restrict__ x,
        const float* __restrict__ wp, const float* __restrict__ wn,
        const float* __restrict__ bp, const float* __restrict__ bn,
        const float* __restrict__ npar, float* __restrict__ partial,
        float* __restrict__ out) {
    const int bid = blockIdx.x;
    const int ch  = bid % NCHK;
    const int pb  = bid / NCHK;
    const int p0  = pb * 16;
    const int m0  = ch * MCH;
    const int t   = threadIdx.x;

    // ---- phase A: zero out[] (stride-split across grid) ----
    {
        float4* out4 = (float4*)out;
        const float4 z = make_float4(0.f, 0.f, 0.f, 0.f);
        for (int i = bid * 256 + t; i < (P_ROWS * N_OUT) / 4; i += NB_MAIN * 256)
            out4[i] = z;
    }

    // ---- phase A: per-block max|w| partial ----
    float v = 0.0f;
    {
        const int nW4 = (N_IN * N_OUT) / 4;          // 25088
        const float4* wp4 = (const float4*)wp;
        const float4* wn4 = (const float4*)wn;
        for (int i = bid * 256 + t; i < nW4; i += NB_MAIN * 256) {
            float4 a = wp4[i], c = wn4[i];
            v = fmaxf(v, fmaxf(fmaxf(fabsf(a.x), fabsf(a.y)), fmaxf(fabsf(a.z), fabsf(a.w))));
            v = fmaxf(v, fmaxf(fmaxf(fabsf(c.x), fabsf(c.y)), fmaxf(fabsf(c.z), fabsf(c.w))));
        }
        if (bid == 0 && t < N_OUT / 4) {
            float4 a = ((const float4*)bp)[t], c = ((const float4*)bn)[t];
            v = fmaxf(v, fmaxf(fmaxf(fabsf(a.x), fabsf(a.y)), fmaxf(fabsf(a.z), fabsf(a.w))));
            v = fmaxf(v, fmaxf(fmaxf(fabsf(c.x), fabsf(c.y)), fmaxf(fabsf(c.z), fabsf(c.w))));
        }
        for (int off = 32; off > 0; off >>= 1)
            v = fmaxf(v, __shfl_down(v, off, 64));
    }
    __shared__ float smax[4];
    if ((t & 63) == 0) smax[t >> 6] = v;

    // ---- phase A: stage F (A-operand) in LDS, fragment order [sq][p] ----
    __shared__ half8 F_lds[36 * 16];               // 9216 B
    const int NF4 = MCH / 4;                       // 18 float4 per row
    for (int idx = t; idx < 16 * NF4; idx += 256) {
        const int p     = idx / NF4;
        const int f4    = idx - p * NF4;
        const int mbase = m0 + f4 * 4;
        float xv[4];
        if (mbase + 3 < N_IN) {
            float4 vx = *(const float4*)(x + (size_t)(p0 + p) * N_IN + mbase);
            xv[0] = vx.x; xv[1] = vx.y; xv[2] = vx.z; xv[3] = vx.w;
        } else {
            #pragma unroll
            for (int u = 0; u < 4; ++u) {
                int m = mbase + u;
                xv[u] = (m < N_IN) ? x[(size_t)(p0 + p) * N_IN + m] : -1.0f;
            }
        }
        #pragma unroll
        for (int u = 0; u < 4; ++u) {
            const int m  = mbase + u;
            const int ml = m - m0;
            float e;
            if (m < N_IN)
                e = (xv[u] > 0.0f) ? __builtin_amdgcn_logf(2.0f * xv[u]) : -1.0e4f;
            else
                e = (m == N_IN) ? 1.0f : -1.0e4f;  // bias row; pads -> F = 0
            float F0 = __builtin_amdgcn_exp2f(e * L_AVG_F);
            float F1 = F0 * e, F2 = F1 * e, F3 = F2 * e;
            _Float16* dst = (_Float16*)&F_lds[(ml >> 1) * 16 + p] + (ml & 1) * 4;
            dst[0] = (_Float16)F0;
            dst[1] = (_Float16)F1;
            dst[2] = (_Float16)F2;
            dst[3] = (_Float16)F3;
        }
    }
    __syncthreads();
    if (t == 0)
        partial[bid] = fmaxf(fmaxf(smax[0], smax[1]), fmaxf(smax[2], smax[3]));

    // ---- grid-wide sync: out[] zeroed, partial[] complete, F_lds staged ----
    cg::this_grid().sync();

    // ---- phase B prologue: global max from 704 partials -> c0 ----
    __shared__ float sred[4];
    {
        float pv = 0.0f;
        for (int i = t; i < NB_MAIN; i += 256)
            pv = fmaxf(pv, partial[i]);
        for (int off = 32; off > 0; off >>= 1)
            pv = fmaxf(pv, __shfl_down(pv, off, 64));
        if ((t & 63) == 0) sred[t >> 6] = pv;
    }
    __syncthreads();
    const float mw = fmaxf(fmaxf(sred[0], sred[1]), fmaxf(sred[2], sred[3]));
    const float c0 = 0.5f * RATIO_F * mw;

    // ---- phase B: MFMA micro-GEMM with on-the-fly B generation ----
    const int lane = t & 63;
    const int w    = t >> 6;
    const int quad = lane >> 4;
    const int col  = lane & 15;
    const int n0   = w * 32;                       // wave covers n0..n0+31
    const int nA   = n0 + col;
    const int nB   = n0 + 16 + col;
    const int mq   = m0 + quad * 2;                // lane's base m

    f32x4 acc0 = {0.f, 0.f, 0.f, 0.f};
    f32x4 acc1 = {0.f, 0.f, 0.f, 0.f};
    #pragma unroll
    for (int s = 0; s < NSTEP; ++s) {
        half8 a = F_lds[(s * 4 + quad) * 16 + col];                    // ds_read_b128
        half8 b0, b1;
        if (s < 8 || ch != NCHK - 1) {
            // all rows are plain weight rows (m <= 783): no guards needed
            #pragma unroll
            for (int bb = 0; bb < 2; ++bb) {
                const int m = mq + s * 8 + bb;
                float CA[4], CB[4];
                genB(m, nA, c0, wp, wn, npar, CA);
                genB(m, nB, c0, wp, wn, npar, CB);
                #pragma unroll
                for (int j = 0; j < 4; ++j) {
                    b0[bb * 4 + j] = (_Float16)CA[j];
                    b1[bb * 4 + j] = (_Float16)CB[j];
                }
            }
        } else {
            // chunk 10, step 8: m = 784..791. Only m==784 (quad 0, bb 0)
            // is real (bias row); the rest are zero-pads.
            #pragma unroll
            for (int j = 0; j < 8; ++j) { b0[j] = (_Float16)0.f; b1[j] = (_Float16)0.f; }
            if (quad == 0) {
                float CA[4], CB[4];
                genBias(nA, c0, bp, bn, npar, CA);
                genBias(nB, c0, bp, bn, npar, CB);
                #pragma unroll
                for (int j = 0; j < 4; ++j) {
                    b0[j] = (_Float16)CA[j];
                    b1[j] = (_Float16)CB[j];
                }
            }
        }
        acc0 = __builtin_amdgcn_mfma_f32_16x16x32_f16(a, b0, acc0, 0, 0, 0);
        acc1 = __builtin_amdgcn_mfma_f32_16x16x32_f16(a, b1, acc1, 0, 0, 0);
    }

    // D layout: row = quad*4 + r, col = lane&15. 8 coalesced f32 atomics/lane.
    float* obase = out + (size_t)(p0 + quad * 4) * N_OUT;
    #pragma unroll
    for (int r = 0; r < 4; ++r) {
        unsafeAtomicAdd(&obase[(size_t)r * N_OUT + n0 + col],      acc0[r]);
        unsafeAtomicAdd(&obase[(size_t)r * N_OUT + n0 + 16 + col], acc1[r]);
    }
}

// ---------------------------------------------------------------------------
extern "C" void kernel_launch(void* const* d_in, const int* in_sizes, int n_in,
                              void* d_out, int out_size, void* d_ws, size_t ws_size,
                              hipStream_t stream) {
    const float* x  = (const float*)d_in[0];
    const float* wp = (const float*)d_in[1];
    const float* wn = (const float*)d_in[2];
    const float* bp = (const float*)d_in[3];
    const float* bn = (const float*)d_in[4];
    const float* np = (const float*)d_in[5];
    float* out = (float*)d_out;

    float* partial = (float*)d_ws;                // NB_MAIN floats

    void* args[] = {(void*)&x, (void*)&wp, (void*)&wn, (void*)&bp,
                    (void*)&bn, (void*)&np, (void*)&partial, (void*)&out};
    hipLaunchCooperativeKernel((const void*)memristor_fused,
                               dim3(NB_MAIN), dim3(256), args, 0, stream);
}

// Round 3
// 76.434 us; speedup vs baseline: 1.8094x; 1.8094x over previous
//
#include <hip/hip_runtime.h>
#include <hip/hip_bf16.h>

// Problem constants
#define P_ROWS   1024
#define N_IN     784
#define N_OUT    128
#define M_ROWS   785                 // N_IN + 1 (bias row)

// RATIO = G_MIN/(G_MAX-G_MIN);  L_AVG = log2(n_avg), n_avg = 2.132
#define RATIO_F  ((float)((1.0/983.3) / ((1.0/281.3) - (1.0/983.3))))
#define L_AVG_F  1.0922076f
#define LN2_F    0.6931472f

// GEMM shape: K = m-rows * 4 Taylor terms. 11 chunks of 72 m-rows (288 K).
// Block tile: 32 p-rows x 64 n-cols. Each wave owns 16 n-cols; its B-fragment
// (genB) is reused by TWO A-tiles (p and p+16) -> genB work halved vs the
// 16x128 tile at the SAME block count / occupancy.
#define NCHK   11
#define MCH    72
#define NSTEP  9                     // 288 K / 32
#define NPB    32                    // 1024/32 p-tiles
#define NB_MAIN (NPB * 2 * NCHK)     // 32 p-tiles x 2 n-halves x 11 chunks = 704

#define NB_MAX 64                    // K1 blocks / max partials

typedef _Float16 half8 __attribute__((ext_vector_type(8)));
typedef float    f32x4 __attribute__((ext_vector_type(4)));

// ---------------------------------------------------------------------------
// K1: per-block max|w| partials over {wp,wn,bp,bn} -> partial[0..63],
//     PLUS zero out[] (each block zeroes an 8 KB slice); out is fully
//     rewritten here before the main kernel accumulates atomically.
__global__ __launch_bounds__(256) void max_reduce_zero(
        const float* __restrict__ wp, const float* __restrict__ wn,
        const float* __restrict__ bp, const float* __restrict__ bn,
        float* __restrict__ partial, float4* __restrict__ out4) {
    const int b = blockIdx.x, t = threadIdx.x;

    // zero this block's slice of out: 64 blocks x 512 float4 = 131072 floats
    const float4 z = make_float4(0.f, 0.f, 0.f, 0.f);
    #pragma unroll
    for (int i = 0; i < 2; ++i)
        out4[(size_t)b * 512 + i * 256 + t] = z;

    const int nW4 = (N_IN * N_OUT) / 4;          // 25088
    const float4* wp4 = (const float4*)wp;
    const float4* wn4 = (const float4*)wn;
    int gid = b * 256 + t;                       // 0..16383
    float v = 0.0f;
    if (gid < N_OUT / 4) {
        float4 a = ((const float4*)bp)[gid], c = ((const float4*)bn)[gid];
        v = fmaxf(fmaxf(fmaxf(fabsf(a.x), fabsf(a.y)), fmaxf(fabsf(a.z), fabsf(a.w))),
                  fmaxf(fmaxf(fabsf(c.x), fabsf(c.y)), fmaxf(fabsf(c.z), fabsf(c.w))));
    }
    for (int i = gid; i < nW4; i += NB_MAX * 256) {
        float4 a = wp4[i], c = wn4[i];
        v = fmaxf(v, fmaxf(fmaxf(fabsf(a.x), fabsf(a.y)), fmaxf(fabsf(a.z), fabsf(a.w))));
        v = fmaxf(v, fmaxf(fmaxf(fabsf(c.x), fabsf(c.y)), fmaxf(fabsf(c.z), fabsf(c.w))));
    }
    for (int off = 32; off > 0; off >>= 1)
        v = fmaxf(v, __shfl_down(v, off, 64));
    __shared__ float smax[4];
    if ((t & 63) == 0) smax[t >> 6] = v;
    __syncthreads();
    if (t == 0)
        partial[b] = fmaxf(fmaxf(smax[0], smax[1]), fmaxf(smax[2], smax[3]));
}

// ---------------------------------------------------------------------------
// On-the-fly Taylor coefficients C_0..C_3 for weight row m, column n.
//   C_0 = 0.5(wp-wn); C_j = (Ap*Dp^j - An*Dn^j)/j!, A = c0 + 0.5w,
//   D = ln(n_param/n_avg).
__device__ __forceinline__ void genB(int m, int n, float c0,
        const float* __restrict__ wp, const float* __restrict__ wn,
        const float* __restrict__ npar, float C[4]) {
    float wpv = wp[(size_t)m * N_OUT + n];
    float wnv = wn[(size_t)m * N_OUT + n];
    float2 nv = *(const float2*)(npar + (size_t)m * (2 * N_OUT) + 2 * n);
    float Dp = LN2_F * (__builtin_amdgcn_logf(nv.x) - L_AVG_F);
    float Dn = LN2_F * (__builtin_amdgcn_logf(nv.y) - L_AVG_F);
    float Ap = c0 + 0.5f * wpv;
    float An = c0 + 0.5f * wnv;
    float ApD = Ap * Dp,    AnD = An * Dn;
    float ApD2 = ApD * Dp,  AnD2 = AnD * Dn;
    float ApD3 = ApD2 * Dp, AnD3 = AnD2 * Dn;
    C[0] = Ap - An;                              // c0 cancels
    C[1] = ApD - AnD;
    C[2] = (ApD2 - AnD2) * 0.5f;
    C[3] = (ApD3 - AnD3) * (1.0f / 6.0f);
}

// Bias row (m == N_IN): weights come from bp/bn.
__device__ __forceinline__ void genBias(int n, float c0,
        const float* __restrict__ bp, const float* __restrict__ bn,
        const float* __restrict__ npar, float C[4]) {
    float wpv = bp[n];
    float wnv = bn[n];
    float2 nv = *(const float2*)(npar + (size_t)N_IN * (2 * N_OUT) + 2 * n);
    float Dp = LN2_F * (__builtin_amdgcn_logf(nv.x) - L_AVG_F);
    float Dn = LN2_F * (__builtin_amdgcn_logf(nv.y) - L_AVG_F);
    float Ap = c0 + 0.5f * wpv;
    float An = c0 + 0.5f * wnv;
    float ApD = Ap * Dp,    AnD = An * Dn;
    float ApD2 = ApD * Dp,  AnD2 = AnD * Dn;
    float ApD3 = ApD2 * Dp, AnD3 = AnD2 * Dn;
    C[0] = Ap - An;
    C[1] = ApD - AnD;
    C[2] = (ApD2 - AnD2) * 0.5f;
    C[3] = (ApD3 - AnD3) * (1.0f / 6.0f);
}

// ---------------------------------------------------------------------------
// Main kernel: MFMA micro-GEMM with on-the-fly B generation.
// 704 blocks (32 p-tiles x 2 n-halves x 11 chunks), 256 thr.
// F (A-operand) staged in LDS in fragment order [sq][p] half8 (32 p-rows).
// Each wave: 16 n-cols; per step 1 B-fragment (2 genB calls) feeds 2 MFMAs
// (p-tiles p0..p0+15 and p0+16..p0+31). genB total halved vs 16x128 tile.
// Epilogue: unsafeAtomicAdd into out (zeroed by K1; 11 adds/output).
__global__ __launch_bounds__(256, 3) void memristor_main(
        const float* __restrict__ x,
        const float* __restrict__ wp, const float* __restrict__ wn,
        const float* __restrict__ bp, const float* __restrict__ bn,
        const float* __restrict__ npar, const float* __restrict__ partial,
        float* __restrict__ out) {
    const int bid = blockIdx.x;
    const int ch  = bid % NCHK;
    const int rem = bid / NCHK;                    // 0..63
    const int pb  = rem >> 1;                      // 0..31
    const int nh  = rem & 1;                       // n-half
    const int p0  = pb * 32;
    const int m0  = ch * MCH;
    const int t   = threadIdx.x;

    // global max|w| from the 64 partials (uniform -> scalar loads, L2-hot)
    float mw = 0.0f;
    #pragma unroll
    for (int i = 0; i < NB_MAX; ++i) mw = fmaxf(mw, partial[i]);
    const float c0 = 0.5f * RATIO_F * mw;

    // ---- stage F (A-operand) in LDS, fragment order [sq][p], 32 p-rows ----
    __shared__ half8 F_lds[36 * 32];               // 18432 B
    const int NF4 = MCH / 4;                       // 18 float4 per row
    for (int idx = t; idx < 32 * NF4; idx += 256) {
        const int p     = idx / NF4;               // 0..31
        const int f4    = idx - p * NF4;
        const int mbase = m0 + f4 * 4;
        float xv[4];
        if (mbase + 3 < N_IN) {
            float4 v = *(const float4*)(x + (size_t)(p0 + p) * N_IN + mbase);
            xv[0] = v.x; xv[1] = v.y; xv[2] = v.z; xv[3] = v.w;
        } else {
            #pragma unroll
            for (int u = 0; u < 4; ++u) {
                int m = mbase + u;
                xv[u] = (m < N_IN) ? x[(size_t)(p0 + p) * N_IN + m] : -1.0f;
            }
        }
        #pragma unroll
        for (int u = 0; u < 4; ++u) {
            const int m  = mbase + u;
            const int ml = m - m0;
            float e;
            if (m < N_IN)
                e = (xv[u] > 0.0f) ? __builtin_amdgcn_logf(2.0f * xv[u]) : -1.0e4f;
            else
                e = (m == N_IN) ? 1.0f : -1.0e4f;  // bias row; pads -> F = 0
            float F0 = __builtin_amdgcn_exp2f(e * L_AVG_F);
            float F1 = F0 * e, F2 = F1 * e, F3 = F2 * e;
            _Float16* dst = (_Float16*)&F_lds[(ml >> 1) * 32 + p] + (ml & 1) * 4;
            dst[0] = (_Float16)F0;
            dst[1] = (_Float16)F1;
            dst[2] = (_Float16)F2;
            dst[3] = (_Float16)F3;
        }
    }
    __syncthreads();

    const int lane = t & 63;
    const int w    = t >> 6;
    const int quad = lane >> 4;
    const int col  = lane & 15;
    const int n    = nh * 64 + w * 16 + col;       // this lane's output column
    const int mq   = m0 + quad * 2;                // lane's base m

    f32x4 acc0 = {0.f, 0.f, 0.f, 0.f};            // p-tile 0 (rows p0..p0+15)
    f32x4 acc1 = {0.f, 0.f, 0.f, 0.f};            // p-tile 1 (rows p0+16..31)
    #pragma unroll
    for (int s = 0; s < NSTEP; ++s) {
        half8 a0 = F_lds[(s * 4 + quad) * 32 + col];                  // ds_read_b128
        half8 a1 = F_lds[(s * 4 + quad) * 32 + 16 + col];
        half8 b;
        if (s < 8 || ch != NCHK - 1) {
            // all rows are plain weight rows (m <= 783): no guards needed
            #pragma unroll
            for (int bb = 0; bb < 2; ++bb) {
                const int m = mq + s * 8 + bb;
                float C[4];
                genB(m, n, c0, wp, wn, npar, C);
                #pragma unroll
                for (int j = 0; j < 4; ++j)
                    b[bb * 4 + j] = (_Float16)C[j];
            }
        } else {
            // chunk 10, step 8: m = 784..791. Only m==784 (quad 0, bb 0)
            // is real (bias row); the rest are zero-pads.
            #pragma unroll
            for (int j = 0; j < 8; ++j) b[j] = (_Float16)0.f;
            if (quad == 0) {
                float C[4];
                genBias(n, c0, bp, bn, npar, C);
                #pragma unroll
                for (int j = 0; j < 4; ++j)
                    b[j] = (_Float16)C[j];
            }
        }
        acc0 = __builtin_amdgcn_mfma_f32_16x16x32_f16(a0, b, acc0, 0, 0, 0);
        acc1 = __builtin_amdgcn_mfma_f32_16x16x32_f16(a1, b, acc1, 0, 0, 0);
    }

    // D layout: row = quad*4 + r, col = lane&15. 8 coalesced f32 atomics/lane.
    float* ob0 = out + (size_t)(p0 + quad * 4) * N_OUT + n;
    float* ob1 = out + (size_t)(p0 + 16 + quad * 4) * N_OUT + n;
    #pragma unroll
    for (int r = 0; r < 4; ++r) {
        unsafeAtomicAdd(&ob0[(size_t)r * N_OUT], acc0[r]);
        unsafeAtomicAdd(&ob1[(size_t)r * N_OUT], acc1[r]);
    }
}

// ---------------------------------------------------------------------------
extern "C" void kernel_launch(void* const* d_in, const int* in_sizes, int n_in,
                              void* d_out, int out_size, void* d_ws, size_t ws_size,
                              hipStream_t stream) {
    const float* x  = (const float*)d_in[0];
    const float* wp = (const float*)d_in[1];
    const float* wn = (const float*)d_in[2];
    const float* bp = (const float*)d_in[3];
    const float* bn = (const float*)d_in[4];
    const float* np = (const float*)d_in[5];
    float* out = (float*)d_out;

    float* partial = (float*)d_ws;                // 64 floats

    max_reduce_zero<<<NB_MAX, 256, 0, stream>>>(wp, wn, bp, bn, partial, (float4*)out);
    memristor_main<<<NB_MAIN, 256, 0, stream>>>(x, wp, wn, bp, bn, np, partial, out);
}